// Round 9
// baseline (257.272 us; speedup 1.0000x reference)
//
#include <hip/hip_runtime.h>
#include <hip/hip_bf16.h>

typedef unsigned short u16;
typedef unsigned long long u64t;
typedef __attribute__((ext_vector_type(8))) short bhalf8;   // 8 x bf16 (4 VGPRs)
typedef __attribute__((ext_vector_type(4))) short bhalf4;   // 4 x bf16 (2 VGPRs)
typedef __attribute__((ext_vector_type(4))) float f32x4;    // MFMA accumulator

#define MFMA16(a, b, c) __builtin_amdgcn_mfma_f32_16x16x32_bf16((a), (b), (c), 0, 0, 0)

#if __has_builtin(__builtin_amdgcn_mfma_f32_16x16x16bf16_1k)
#define HAVE_K16 1
#define MFMAK16(a, b, c) __builtin_amdgcn_mfma_f32_16x16x16bf16_1k((a), (b), (c), 0, 0, 0)
#elif __has_builtin(__builtin_amdgcn_mfma_f32_16x16x16_bf16)
#define HAVE_K16 1
#define MFMAK16(a, b, c) __builtin_amdgcn_mfma_f32_16x16x16_bf16((a), (b), (c), 0, 0, 0)
#else
#define HAVE_K16 0
#endif

#define BB 2
#define SS 2048
#define DD 512
#define HH 8
#define HD 64
#define NT (BB * SS)
#define LOG2E 1.44269504f

#if __has_builtin(__builtin_amdgcn_exp2f)
#define EXP2(x) __builtin_amdgcn_exp2f(x)
#else
#define EXP2(x) exp2f(x)
#endif

__device__ __forceinline__ u16 f2b(float f) {
    unsigned u = __builtin_bit_cast(unsigned, f);
    unsigned r = (u + 0x7fffu + ((u >> 16) & 1u)) >> 16;
    return (u16)r;
}

__device__ __forceinline__ void gl2lds16(const u16* g, u16* l) {
    u16* gn = (u16*)g;
    __builtin_amdgcn_global_load_lds((__attribute__((address_space(1))) void*)gn,
                                     (__attribute__((address_space(3))) void*)l, 16, 0, 0);
}

// ---------------------------------------------------------------------------
// Fused weight prep: fp32->bf16 transposes + qkv bias concat
// ---------------------------------------------------------------------------
__global__ __launch_bounds__(256) void k_prep(const float* __restrict__ Wq, const float* __restrict__ Wk,
                                              const float* __restrict__ Wv, const float* __restrict__ Wp,
                                              const float* __restrict__ W1, const float* __restrict__ W2,
                                              const float* __restrict__ bq, const float* __restrict__ bk,
                                              const float* __restrict__ bv,
                                              u16* __restrict__ WqkvT, u16* __restrict__ WpT,
                                              u16* __restrict__ W1T, u16* __restrict__ W2T,
                                              float* __restrict__ biasqkv) {
    int j = blockIdx.x;
    int tx = threadIdx.x, ty = threadIdx.y;   // (32,8)
    if (j >= 3072) {
        int i = (j - 3072) * 256 + ty * 32 + tx;
        biasqkv[i] = (i < 512) ? bq[i] : (i < 1024) ? bk[i - 512] : bv[i - 1024];
        return;
    }
    __shared__ float tile[32][33];
    const float* src; u16* dst; int R, C, tr, tc;
    if (j < 768) {            // Wq/Wk/Wv per-head [512,64] -> [64,512]
        int m = j >> 8, rem = j & 255, h = rem >> 5, tl = rem & 31;
        tr = tl >> 1; tc = tl & 1;
        src = (m == 0 ? Wq : (m == 1 ? Wk : Wv)) + h * 32768;
        dst = WqkvT + m * 262144 + h * 32768;
        R = 512; C = 64;
    } else if (j < 1024) { int tl = j - 768;  tr = tl >> 4; tc = tl & 15; src = Wp; dst = WpT; R = 512;  C = 512;  }
    else if (j < 2048)   { int tl = j - 1024; tr = tl >> 6; tc = tl & 63; src = W1; dst = W1T; R = 512;  C = 2048; }
    else                 { int tl = j - 2048; tr = tl >> 4; tc = tl & 15; src = W2; dst = W2T; R = 2048; C = 512;  }
    int c = tc * 32 + tx;
#pragma unroll
    for (int i = 0; i < 4; i++)
        tile[ty + i * 8][tx] = src[(size_t)(tr * 32 + ty + i * 8) * C + c];
    __syncthreads();
    int r2 = tr * 32 + tx;
#pragma unroll
    for (int i = 0; i < 4; i++)
        dst[(size_t)(tc * 32 + ty + i * 8) * R + r2] = f2b(tile[tx][ty + i * 8]);
}

// ---------------------------------------------------------------------------
// LayerNorm: one wave per 512-col row; fp32 in, bf16 out
// ---------------------------------------------------------------------------
__global__ __launch_bounds__(256) void k_layernorm(const float* __restrict__ x,
                                                   const float* __restrict__ g,
                                                   const float* __restrict__ be,
                                                   u16* __restrict__ out) {
    int wave = threadIdx.x >> 6, lane = threadIdx.x & 63;
    int row = blockIdx.x * 4 + wave;
    const float* xr = x + (size_t)row * DD;
    int c = lane * 8;
    float4 v0 = *(const float4*)(xr + c);
    float4 v1 = *(const float4*)(xr + c + 4);
    float s  = v0.x + v0.y + v0.z + v0.w + v1.x + v1.y + v1.z + v1.w;
    float sq = v0.x*v0.x + v0.y*v0.y + v0.z*v0.z + v0.w*v0.w
             + v1.x*v1.x + v1.y*v1.y + v1.z*v1.z + v1.w*v1.w;
#pragma unroll
    for (int m = 1; m < 64; m <<= 1) {
        s  += __shfl_xor(s, m);
        sq += __shfl_xor(sq, m);
    }
    float mean = s * (1.0f / DD);
    float var  = sq * (1.0f / DD) - mean * mean;
    float rstd = rsqrtf(var + 1e-5f);
    float4 g0 = *(const float4*)(g + c);
    float4 g1 = *(const float4*)(g + c + 4);
    float4 b0 = *(const float4*)(be + c);
    float4 b1 = *(const float4*)(be + c + 4);
    float xv[8] = {v0.x, v0.y, v0.z, v0.w, v1.x, v1.y, v1.z, v1.w};
    float gv[8] = {g0.x, g0.y, g0.z, g0.w, g1.x, g1.y, g1.z, g1.w};
    float bv[8] = {b0.x, b0.y, b0.z, b0.w, b1.x, b1.y, b1.z, b1.w};
    union { bhalf8 v; u16 u[8]; } pk;
#pragma unroll
    for (int i = 0; i < 8; i++) pk.u[i] = f2b((xv[i] - mean) * rstd * gv[i] + bv[i]);
    *(bhalf8*)(out + (size_t)row * DD + c) = pk.v;
}

// ---------------------------------------------------------------------------
// bf16 MFMA GEMM, BMxBN tile, BK=64, gl2lds staging (8-row x 64-col 1KB chunks)
// MODE 0: qkv scatter (q scaled by log2e, v transposed [bh,hd,S])
// MODE 1: out fp32 = val + bias + resid
// MODE 2: out bf16 = relu(val + bias)
// ---------------------------------------------------------------------------
template<int BM, int BN, int WR, int WC, int MI, int NI, int MODE>
__global__ __launch_bounds__(256) void k_gemm(const u16* __restrict__ A, const u16* __restrict__ Bt,
                                              const float* __restrict__ bias,
                                              int lda, int ldb, int kLen, int N,
                                              const float* __restrict__ resid,
                                              float* __restrict__ outF, u16* __restrict__ outB,
                                              u16* __restrict__ qd, u16* __restrict__ kd,
                                              u16* __restrict__ vtd) {
    constexpr int WM = MI * 16;
    constexpr int WN = NI * 16;
    static_assert(WR * WM == BM && WC * WN == BN && WR * WC == 4, "cfg");
    constexpr int ACH = BM / 32;          // A staging chunks per wave (8 rows each)
    constexpr int BCH = BN / 32;
    __shared__ u16 As[BM * 64];
    __shared__ u16 Bs[BN * 64];
    int t = threadIdx.x;
    int wave = t >> 6, lane = t & 63, quad = lane >> 4, l16 = lane & 15;
    int wr, wc;
    if (WC == 1)      { wr = wave; wc = 0; }
    else if (WR == 1) { wr = 0;    wc = wave; }
    else              { wr = wave >> 1; wc = wave & 1; }
    int m0 = blockIdx.y * BM, n0 = blockIdx.x * BN;

    f32x4 acc[MI][NI] = {};

    int srow = lane >> 3;                 // 0..7
    int scol = (lane & 7) * 8;
    const u16* Ag = A  + (size_t)(m0 + srow) * lda + scol;
    const u16* Bg = Bt + (size_t)(n0 + srow) * ldb + scol;

    for (int k0 = 0; k0 < kLen; k0 += 64) {
        __syncthreads();
#pragma unroll
        for (int c = 0; c < ACH; c++) {
            int ch = wave * ACH + c;
            gl2lds16(Ag + (size_t)(ch * 8) * lda + k0, &As[ch * 512]);
        }
#pragma unroll
        for (int c = 0; c < BCH; c++) {
            int ch = wave * BCH + c;
            gl2lds16(Bg + (size_t)(ch * 8) * ldb + k0, &Bs[ch * 512]);
        }
        __syncthreads();
#pragma unroll
        for (int h = 0; h < 2; h++) {
            bhalf8 af[MI], bf[NI];
#pragma unroll
            for (int mi = 0; mi < MI; mi++)
                af[mi] = *(bhalf8*)&As[(wr * WM + mi * 16 + l16) * 64 + h * 32 + quad * 8];
#pragma unroll
            for (int ni = 0; ni < NI; ni++)
                bf[ni] = *(bhalf8*)&Bs[(wc * WN + ni * 16 + l16) * 64 + h * 32 + quad * 8];
#pragma unroll
            for (int mi = 0; mi < MI; mi++)
#pragma unroll
                for (int ni = 0; ni < NI; ni++)
                    acc[mi][ni] = MFMA16(af[mi], bf[ni], acc[mi][ni]);
        }
    }

#pragma unroll
    for (int mi = 0; mi < MI; mi++)
#pragma unroll
        for (int ni = 0; ni < NI; ni++) {
            f32x4 a = acc[mi][ni];
            int gc = n0 + wc * WN + ni * 16 + l16;
            int gr0 = m0 + wr * WM + mi * 16 + quad * 4;
            float bsv = bias[gc];
            if (MODE == 0) {
                int mm = gc >> 9, cc = gc & 511;
                int hh = cc >> 6, e = cc & 63;
                int b = gr0 >> 11, s0 = gr0 & 2047;
                if (mm == 2) {
                    u64t pk = 0;
#pragma unroll
                    for (int r = 0; r < 4; r++) pk |= (u64t)f2b(a[r] + bsv) << (16 * r);
                    *(u64t*)&vtd[((size_t)(b * HH + hh) * HD + e) * SS + s0] = pk;
                } else if (mm == 0) {
#pragma unroll
                    for (int r = 0; r < 4; r++)
                        qd[((size_t)(b * HH + hh) * SS + s0 + r) * HD + e] = f2b((a[r] + bsv) * LOG2E);
                } else {
#pragma unroll
                    for (int r = 0; r < 4; r++)
                        kd[((size_t)(b * HH + hh) * SS + s0 + r) * HD + e] = f2b(a[r] + bsv);
                }
            } else if (MODE == 1) {
#pragma unroll
                for (int r = 0; r < 4; r++) {
                    size_t idx = (size_t)(gr0 + r) * N + gc;
                    outF[idx] = a[r] + bsv + resid[idx];
                }
            } else {
#pragma unroll
                for (int r = 0; r < 4; r++)
                    outB[(size_t)(gr0 + r) * N + gc] = f2b(fmaxf(a[r] + bsv, 0.0f));
            }
        }
}

// ---------------------------------------------------------------------------
// Flash attention v6: K double-buffered LDS via EXPLICIT padded stores
// (stride 72 honored — gl2lds cannot pad), ONE barrier per iter; V read
// directly from global Vt (L2-resident, off the critical chain).
// S^T trick, q-tile 128, kv-tile 128 in 2 wave-groups, split-KV x2.
// grid (16 bh, 16 q-tiles, 2 kv-splits); 512 threads = 8 waves.
// ---------------------------------------------------------------------------
__global__ __launch_bounds__(512) void k_attention(const u16* __restrict__ q,
                                                   const u16* __restrict__ k,
                                                   const u16* __restrict__ vt,
                                                   float* __restrict__ Opart,
                                                   float* __restrict__ lsum) {
    __shared__ u16 Ks[2][128 * 72];           // 36,864 B, [kv][hd] stride 72
    float* Ored = (float*)&Ks[0][0];          // epilogue overlay: 8192 f32
    float* Lred = (float*)&Ks[0][0] + 8192;   // 128 f32 (total 33,280 B)

    int bh = blockIdx.x, qt = blockIdx.y, kspl = blockIdx.z;
    int t = threadIdx.x, wave = t >> 6, lane = t & 63, quad = lane >> 4, l16 = lane & 15;
    int g = wave >> 2, qw = wave & 3;         // kv-group, q-subtile
    const u16* qb = q  + (size_t)bh * SS * HD;
    const u16* kb = k  + (size_t)bh * SS * HD;
    const u16* vb = vt + (size_t)bh * HD * SS;

    // two q-chunks of 16 rows per wave (identical across groups)
    bhalf8 qfa0, qfa1, qfb0, qfb1;
    {
        int r0 = qt * 128 + qw * 32 + l16;
        qfa0 = *(const bhalf8*)(qb + (size_t)r0 * HD + quad * 8);
        qfa1 = *(const bhalf8*)(qb + (size_t)r0 * HD + 32 + quad * 8);
        qfb0 = *(const bhalf8*)(qb + (size_t)(r0 + 16) * HD + quad * 8);
        qfb1 = *(const bhalf8*)(qb + (size_t)(r0 + 16) * HD + 32 + quad * 8);
    }

    f32x4 oacc[2][4] = {};
    float rsa = 0.f, rsb = 0.f;

    // K staging: 512 threads x 32B; kr = row (0..127), kc = 16*u16 col chunk
    int kr = t >> 2, kc = (t & 3) * 16;
    const u16* kp = kb + ((size_t)kspl * 1024 + kr) * HD + kc;
    u16* ksd0 = &Ks[0][kr * 72 + kc];
    u16* ksd1 = &Ks[1][kr * 72 + kc];
    // V direct-from-global base for this lane's frag rows
    const u16* Vgl = vb + (size_t)kspl * 1024 + g * 64 + quad * 4;

    // prologue: load tile 0 into regs
    bhalf8 kreg0 = *(const bhalf8*)(kp);
    bhalf8 kreg1 = *(const bhalf8*)(kp + 8);

    for (int it = 0; it < 8; it++) {
        u16* ksd = (it & 1) ? ksd1 : ksd0;
        *(bhalf8*)ksd = kreg0;
        *(bhalf8*)(ksd + 8) = kreg1;
        __syncthreads();                       // lgkm drain: stores visible
        if (it < 7) {                          // prefetch tile it+1 (global, async)
            const u16* kn = kp + (size_t)(it + 1) * 128 * HD;
            kreg0 = *(const bhalf8*)(kn);
            kreg1 = *(const bhalf8*)(kn + 8);
        }
        const u16* Kb = &Ks[it & 1][0];
        const u16* Vit = Vgl + it * 128;

#pragma unroll
        for (int nt2 = 0; nt2 < 4; nt2++) {
            int nt = g * 4 + nt2;
            bhalf8 kf0 = *(const bhalf8*)&Kb[(nt * 16 + l16) * 72 + quad * 8];
            bhalf8 kf1 = *(const bhalf8*)&Kb[(nt * 16 + l16) * 72 + 32 + quad * 8];
            // S^T = K·Q^T (C-layout: col=l16=q, row=quad*4+r=kv)
            f32x4 sa = {}, sb = {};
            sa = MFMA16(kf0, qfa0, sa);
            sa = MFMA16(kf1, qfa1, sa);
            sb = MFMA16(kf0, qfb0, sb);
            sb = MFMA16(kf1, qfb1, sb);
#if HAVE_K16
            union { bhalf4 v; u16 u[4]; } pa, pb;
#pragma unroll
            for (int r = 0; r < 4; r++) {
                float p0 = EXP2(sa[r]);
                float p1 = EXP2(sb[r]);
                rsa += p0; rsb += p1;
                pa.u[r] = f2b(p0); pb.u[r] = f2b(p1);
            }
#pragma unroll
            for (int et = 0; et < 4; et++) {
                bhalf4 vf = *(const bhalf4*)(Vit + (size_t)(et * 16 + l16) * SS + nt2 * 16);
                oacc[0][et] = MFMAK16(pa.v, vf, oacc[0][et]);
                oacc[1][et] = MFMAK16(pb.v, vf, oacc[1][et]);
            }
#else
            union { bhalf8 v; u16 u[8]; } pa, pb;
#pragma unroll
            for (int r = 0; r < 4; r++) {
                float p0 = EXP2(sa[r]);
                float p1 = EXP2(sb[r]);
                rsa += p0; rsb += p1;
                pa.u[r] = f2b(p0); pb.u[r] = f2b(p1);
            }
#pragma unroll
            for (int r = 4; r < 8; r++) { pa.u[r] = 0; pb.u[r] = 0; }
#pragma unroll
            for (int et = 0; et < 4; et++) {
                union { bhalf8 v; bhalf4 h[2]; } vf;
                vf.h[0] = *(const bhalf4*)(Vit + (size_t)(et * 16 + l16) * SS + nt2 * 16);
                vf.h[1] = (bhalf4){0, 0, 0, 0};
                oacc[0][et] = MFMA16(pa.v, vf.v, oacc[0][et]);
                oacc[1][et] = MFMA16(pb.v, vf.v, oacc[1][et]);
            }
#endif
        }
    }

    rsa += __shfl_xor(rsa, 16); rsa += __shfl_xor(rsa, 32);
    rsb += __shfl_xor(rsb, 16); rsb += __shfl_xor(rsb, 32);

    __syncthreads();   // Ks dead; overlay as Ored/Lred
    if (g == 1) {
#pragma unroll
        for (int qc = 0; qc < 2; qc++)
#pragma unroll
            for (int et = 0; et < 4; et++)
#pragma unroll
                for (int r = 0; r < 4; r++)
                    Ored[(qw * 32 + qc * 16 + quad * 4 + r) * 64 + et * 16 + l16] = oacc[qc][et][r];
        if (quad == 0) {
            Lred[qw * 32 + l16]      = rsa;
            Lred[qw * 32 + 16 + l16] = rsb;
        }
    }
    __syncthreads();
    if (g == 0) {
#pragma unroll
        for (int qc = 0; qc < 2; qc++) {
            int sbase = qt * 128 + qw * 32 + qc * 16;
            float* Ob = Opart + ((size_t)(kspl * 16 + bh) * SS + sbase) * HD;
#pragma unroll
            for (int et = 0; et < 4; et++)
#pragma unroll
                for (int r = 0; r < 4; r++) {
                    float v = oacc[qc][et][r]
                            + Ored[(qw * 32 + qc * 16 + quad * 4 + r) * 64 + et * 16 + l16];
                    Ob[(quad * 4 + r) * HD + et * 16 + l16] = v;
                }
            if (quad == 0)
                lsum[(size_t)(kspl * 16 + bh) * SS + sbase + l16] =
                    (qc == 0 ? rsa : rsb) + Lred[qw * 32 + qc * 16 + l16];
        }
    }
}

// combine: oc[b,s,h*64+e] = (O0+O1)/(l0+l1), bf16
__global__ __launch_bounds__(256) void k_combine(const float* __restrict__ Opart,
                                                 const float* __restrict__ lsum,
                                                 u16* __restrict__ oc) {
    int tid = blockIdx.x * 256 + threadIdx.x;
    int c4 = tid & 15, s = (tid >> 4) & 2047, bh = tid >> 15;
    size_t i0 = ((size_t)bh * SS + s) * HD + c4 * 4;
    float4 p0 = *(const float4*)(Opart + i0);
    float4 p1 = *(const float4*)(Opart + (size_t)16 * SS * HD + i0);
    float l = lsum[(size_t)bh * SS + s] + lsum[(size_t)16 * SS + (size_t)bh * SS + s];
    float inv = 1.0f / l;
    u64t pk = 0;
    pk |= (u64t)f2b((p0.x + p1.x) * inv);
    pk |= (u64t)f2b((p0.y + p1.y) * inv) << 16;
    pk |= (u64t)f2b((p0.z + p1.z) * inv) << 32;
    pk |= (u64t)f2b((p0.w + p1.w) * inv) << 48;
    int b = bh >> 3, h = bh & 7;
    *(u64t*)&oc[((size_t)b * SS + s) * DD + h * HD + c4 * 4] = pk;
}

// ---------------------------------------------------------------------------
extern "C" void kernel_launch(void* const* d_in, const int* in_sizes, int n_in,
                              void* d_out, int out_size, void* d_ws, size_t ws_size,
                              hipStream_t stream) {
    const float* x   = (const float*)d_in[0];
    const float* Wq  = (const float*)d_in[1];
    const float* bq  = (const float*)d_in[2];
    const float* Wk  = (const float*)d_in[3];
    const float* bk  = (const float*)d_in[4];
    const float* Wv  = (const float*)d_in[5];
    const float* bv  = (const float*)d_in[6];
    const float* Wp  = (const float*)d_in[7];
    const float* bp  = (const float*)d_in[8];
    const float* W1  = (const float*)d_in[9];
    const float* b1  = (const float*)d_in[10];
    const float* W2  = (const float*)d_in[11];
    const float* b2  = (const float*)d_in[12];
    const float* g1  = (const float*)d_in[13];
    const float* be1 = (const float*)d_in[14];
    const float* g2  = (const float*)d_in[15];
    const float* be2 = (const float*)d_in[16];

    char* ws = (char*)d_ws;
    u16*   WqkvT   = (u16*)(ws + 0);                    // 1,572,864
    u16*   WpT     = (u16*)(ws + 1572864);              //   524,288
    u16*   W1T     = (u16*)(ws + 2097152);              // 2,097,152
    u16*   W2T     = (u16*)(ws + 4194304);              // 2,097,152
    float* biasqkv = (float*)(ws + 6291456);            // 6,144
    u16*   xn      = (u16*)(ws + 6297600);              // 4,194,304 (reused: lsum)
    u16*   qB      = (u16*)(ws + 10491904);             // 4,194,304
    u16*   kB      = (u16*)(ws + 14686208);             // 4,194,304
    u16*   vTb     = (u16*)(ws + 18880512);             // 4,194,304  [bh,hd,S]
    u16*   oc      = (u16*)(ws + 23074816);             // 4,194,304
    float* x1      = (float*)(ws + 27269120);           // 8,388,608
    u16*   xn2     = (u16*)(ws + 35657728);             // 4,194,304
    u16*   hbuf    = (u16*)(ws + 39852032);             // 16,777,216 (Opart before MLP1)
    float* Opart   = (float*)hbuf;
    float* lsum    = (float*)xn;

    k_prep<<<3078, dim3(32, 8), 0, stream>>>(Wq, Wk, Wv, Wp, W1, W2, bq, bk, bv,
                                             WqkvT, WpT, W1T, W2T, biasqkv);
    k_layernorm<<<NT / 4, 256, 0, stream>>>(x, g1, be1, xn);
    // QKV: 128x128 BK=64 m97-style, 32 MFMA/step, grid 384
    k_gemm<128, 128, 2, 2, 4, 4, 0><<<dim3(12, 32), 256, 0, stream>>>(
        xn, WqkvT, biasqkv, 512, 512, 512, 1536, nullptr, nullptr, nullptr, qB, kB, vTb);
    // attention: 8-wave blocks, K-dbuf explicit padded stores, 1 barrier/iter
    k_attention<<<dim3(16, 16, 2), 512, 0, stream>>>(qB, kB, vTb, Opart, lsum);
    k_combine<<<2048, 256, 0, stream>>>(Opart, lsum, oc);
    // proj + residual: 64x64 BK=64, grid 512
    k_gemm<64, 64, 2, 2, 2, 2, 1><<<dim3(8, 64), 256, 0, stream>>>(
        oc, WpT, bp, 512, 512, 512, 512, x, x1, nullptr, nullptr, nullptr, nullptr);
    k_layernorm<<<NT / 4, 256, 0, stream>>>(x1, g2, be2, xn2);
    // MLP1: 128x128 BK=64, grid 512
    k_gemm<128, 128, 2, 2, 4, 4, 2><<<dim3(16, 32), 256, 0, stream>>>(
        xn2, W1T, b1, 512, 512, 512, 2048, nullptr, nullptr, hbuf, nullptr, nullptr, nullptr);
    // MLP2 + residual: 64x64 BK=64, K=2048, grid 512
    k_gemm<64, 64, 2, 2, 2, 2, 1><<<dim3(8, 64), 256, 0, stream>>>(
        hbuf, W2T, b2, 2048, 2048, 2048, 512, x1, (float*)d_out, nullptr, nullptr, nullptr, nullptr);
}

// Round 10
// 208.920 us; speedup vs baseline: 1.2314x; 1.2314x over previous
//
#include <hip/hip_runtime.h>
#include <hip/hip_bf16.h>

typedef unsigned short u16;
typedef unsigned long long u64t;
typedef __attribute__((ext_vector_type(8))) short bhalf8;   // 8 x bf16 (4 VGPRs)
typedef __attribute__((ext_vector_type(4))) short bhalf4;   // 4 x bf16 (2 VGPRs)
typedef __attribute__((ext_vector_type(4))) float f32x4;    // MFMA accumulator

#define MFMA16(a, b, c) __builtin_amdgcn_mfma_f32_16x16x32_bf16((a), (b), (c), 0, 0, 0)

#if __has_builtin(__builtin_amdgcn_mfma_f32_16x16x16bf16_1k)
#define HAVE_K16 1
#define MFMAK16(a, b, c) __builtin_amdgcn_mfma_f32_16x16x16bf16_1k((a), (b), (c), 0, 0, 0)
#elif __has_builtin(__builtin_amdgcn_mfma_f32_16x16x16_bf16)
#define HAVE_K16 1
#define MFMAK16(a, b, c) __builtin_amdgcn_mfma_f32_16x16x16_bf16((a), (b), (c), 0, 0, 0)
#else
#define HAVE_K16 0
#endif

#define BB 2
#define SS 2048
#define DD 512
#define HH 8
#define HD 64
#define NT (BB * SS)
#define LOG2E 1.44269504f

#if __has_builtin(__builtin_amdgcn_exp2f)
#define EXP2(x) __builtin_amdgcn_exp2f(x)
#else
#define EXP2(x) exp2f(x)
#endif

__device__ __forceinline__ u16 f2b(float f) {
    unsigned u = __builtin_bit_cast(unsigned, f);
    unsigned r = (u + 0x7fffu + ((u >> 16) & 1u)) >> 16;
    return (u16)r;
}

__device__ __forceinline__ void gl2lds16(const u16* g, u16* l) {
    u16* gn = (u16*)g;
    __builtin_amdgcn_global_load_lds((__attribute__((address_space(1))) void*)gn,
                                     (__attribute__((address_space(3))) void*)l, 16, 0, 0);
}

// ---------------------------------------------------------------------------
// Fused prep: weight transposes (jobs 0..3071) + qkv bias concat (3072..3077)
// + LayerNorm1 rows (3078..4101; 4 rows/block). LN is independent of weights.
// ---------------------------------------------------------------------------
__global__ __launch_bounds__(256) void k_prep(const float* __restrict__ Wq, const float* __restrict__ Wk,
                                              const float* __restrict__ Wv, const float* __restrict__ Wp,
                                              const float* __restrict__ W1, const float* __restrict__ W2,
                                              const float* __restrict__ bq, const float* __restrict__ bk,
                                              const float* __restrict__ bv,
                                              u16* __restrict__ WqkvT, u16* __restrict__ WpT,
                                              u16* __restrict__ W1T, u16* __restrict__ W2T,
                                              float* __restrict__ biasqkv,
                                              const float* __restrict__ x, const float* __restrict__ g1,
                                              const float* __restrict__ be1, u16* __restrict__ xn) {
    int j = blockIdx.x;
    int t = threadIdx.x;
    if (j >= 3078) {                           // LayerNorm1: 4 rows per block
        int wave = t >> 6, lane = t & 63;
        int row = (j - 3078) * 4 + wave;
        const float* xr = x + (size_t)row * DD;
        int c = lane * 8;
        float4 v0 = *(const float4*)(xr + c);
        float4 v1 = *(const float4*)(xr + c + 4);
        float s  = v0.x + v0.y + v0.z + v0.w + v1.x + v1.y + v1.z + v1.w;
        float sq = v0.x*v0.x + v0.y*v0.y + v0.z*v0.z + v0.w*v0.w
                 + v1.x*v1.x + v1.y*v1.y + v1.z*v1.z + v1.w*v1.w;
#pragma unroll
        for (int m = 1; m < 64; m <<= 1) {
            s  += __shfl_xor(s, m);
            sq += __shfl_xor(sq, m);
        }
        float mean = s * (1.0f / DD);
        float var  = sq * (1.0f / DD) - mean * mean;
        float rstd = rsqrtf(var + 1e-5f);
        float4 g0 = *(const float4*)(g1 + c);
        float4 g4 = *(const float4*)(g1 + c + 4);
        float4 b0 = *(const float4*)(be1 + c);
        float4 b4 = *(const float4*)(be1 + c + 4);
        float xv[8] = {v0.x, v0.y, v0.z, v0.w, v1.x, v1.y, v1.z, v1.w};
        float gv[8] = {g0.x, g0.y, g0.z, g0.w, g4.x, g4.y, g4.z, g4.w};
        float bv2[8] = {b0.x, b0.y, b0.z, b0.w, b4.x, b4.y, b4.z, b4.w};
        union { bhalf8 v; u16 u[8]; } pk;
#pragma unroll
        for (int i = 0; i < 8; i++) pk.u[i] = f2b((xv[i] - mean) * rstd * gv[i] + bv2[i]);
        *(bhalf8*)(xn + (size_t)row * DD + c) = pk.v;
        return;
    }
    int tx = t & 31, ty = t >> 5;              // (32,8) mapping
    if (j >= 3072) {                           // bias concat
        int i = (j - 3072) * 256 + ty * 32 + tx;
        biasqkv[i] = (i < 512) ? bq[i] : (i < 1024) ? bk[i - 512] : bv[i - 1024];
        return;
    }
    __shared__ float tile[32][33];
    const float* src; u16* dst; int R, C, tr, tc;
    if (j < 768) {            // Wq/Wk/Wv per-head [512,64] -> [64,512]
        int m = j >> 8, rem = j & 255, h = rem >> 5, tl = rem & 31;
        tr = tl >> 1; tc = tl & 1;
        src = (m == 0 ? Wq : (m == 1 ? Wk : Wv)) + h * 32768;
        dst = WqkvT + m * 262144 + h * 32768;
        R = 512; C = 64;
    } else if (j < 1024) { int tl = j - 768;  tr = tl >> 4; tc = tl & 15; src = Wp; dst = WpT; R = 512;  C = 512;  }
    else if (j < 2048)   { int tl = j - 1024; tr = tl >> 6; tc = tl & 63; src = W1; dst = W1T; R = 512;  C = 2048; }
    else                 { int tl = j - 2048; tr = tl >> 4; tc = tl & 15; src = W2; dst = W2T; R = 2048; C = 512;  }
    int c = tc * 32 + tx;
#pragma unroll
    for (int i = 0; i < 4; i++)
        tile[ty + i * 8][tx] = src[(size_t)(tr * 32 + ty + i * 8) * C + c];
    __syncthreads();
    int r2 = tr * 32 + tx;
#pragma unroll
    for (int i = 0; i < 4; i++)
        dst[(size_t)(tc * 32 + ty + i * 8) * R + r2] = f2b(tile[tx][ty + i * 8]);
}

// ---------------------------------------------------------------------------
// LayerNorm: one wave per 512-col row; fp32 in, bf16 out  (used for LN2)
// ---------------------------------------------------------------------------
__global__ __launch_bounds__(256) void k_layernorm(const float* __restrict__ x,
                                                   const float* __restrict__ g,
                                                   const float* __restrict__ be,
                                                   u16* __restrict__ out) {
    int wave = threadIdx.x >> 6, lane = threadIdx.x & 63;
    int row = blockIdx.x * 4 + wave;
    const float* xr = x + (size_t)row * DD;
    int c = lane * 8;
    float4 v0 = *(const float4*)(xr + c);
    float4 v1 = *(const float4*)(xr + c + 4);
    float s  = v0.x + v0.y + v0.z + v0.w + v1.x + v1.y + v1.z + v1.w;
    float sq = v0.x*v0.x + v0.y*v0.y + v0.z*v0.z + v0.w*v0.w
             + v1.x*v1.x + v1.y*v1.y + v1.z*v1.z + v1.w*v1.w;
#pragma unroll
    for (int m = 1; m < 64; m <<= 1) {
        s  += __shfl_xor(s, m);
        sq += __shfl_xor(sq, m);
    }
    float mean = s * (1.0f / DD);
    float var  = sq * (1.0f / DD) - mean * mean;
    float rstd = rsqrtf(var + 1e-5f);
    float4 g0 = *(const float4*)(g + c);
    float4 g1 = *(const float4*)(g + c + 4);
    float4 b0 = *(const float4*)(be + c);
    float4 b1 = *(const float4*)(be + c + 4);
    float xv[8] = {v0.x, v0.y, v0.z, v0.w, v1.x, v1.y, v1.z, v1.w};
    float gv[8] = {g0.x, g0.y, g0.z, g0.w, g1.x, g1.y, g1.z, g1.w};
    float bv[8] = {b0.x, b0.y, b0.z, b0.w, b1.x, b1.y, b1.z, b1.w};
    union { bhalf8 v; u16 u[8]; } pk;
#pragma unroll
    for (int i = 0; i < 8; i++) pk.u[i] = f2b((xv[i] - mean) * rstd * gv[i] + bv[i]);
    *(bhalf8*)(out + (size_t)row * DD + c) = pk.v;
}

// ---------------------------------------------------------------------------
// bf16 MFMA GEMM, BMxBN tile, BK=64, gl2lds staging (8-row x 64-col 1KB chunks)
// MODE 0: qkv scatter (q scaled by log2e, v transposed [bh,hd,S])
// MODE 1: out fp32 = val + bias + resid
// MODE 2: out bf16 = relu(val + bias)
// ---------------------------------------------------------------------------
template<int BM, int BN, int WR, int WC, int MI, int NI, int MODE>
__global__ __launch_bounds__(256) void k_gemm(const u16* __restrict__ A, const u16* __restrict__ Bt,
                                              const float* __restrict__ bias,
                                              int lda, int ldb, int kLen, int N,
                                              const float* __restrict__ resid,
                                              float* __restrict__ outF, u16* __restrict__ outB,
                                              u16* __restrict__ qd, u16* __restrict__ kd,
                                              u16* __restrict__ vtd) {
    constexpr int WM = MI * 16;
    constexpr int WN = NI * 16;
    static_assert(WR * WM == BM && WC * WN == BN && WR * WC == 4, "cfg");
    constexpr int ACH = BM / 32;          // A staging chunks per wave (8 rows each)
    constexpr int BCH = BN / 32;
    __shared__ u16 As[BM * 64];
    __shared__ u16 Bs[BN * 64];
    int t = threadIdx.x;
    int wave = t >> 6, lane = t & 63, quad = lane >> 4, l16 = lane & 15;
    int wr, wc;
    if (WC == 1)      { wr = wave; wc = 0; }
    else if (WR == 1) { wr = 0;    wc = wave; }
    else              { wr = wave >> 1; wc = wave & 1; }
    int m0 = blockIdx.y * BM, n0 = blockIdx.x * BN;

    f32x4 acc[MI][NI] = {};

    int srow = lane >> 3;                 // 0..7
    int scol = (lane & 7) * 8;
    const u16* Ag = A  + (size_t)(m0 + srow) * lda + scol;
    const u16* Bg = Bt + (size_t)(n0 + srow) * ldb + scol;

    for (int k0 = 0; k0 < kLen; k0 += 64) {
        __syncthreads();
#pragma unroll
        for (int c = 0; c < ACH; c++) {
            int ch = wave * ACH + c;
            gl2lds16(Ag + (size_t)(ch * 8) * lda + k0, &As[ch * 512]);
        }
#pragma unroll
        for (int c = 0; c < BCH; c++) {
            int ch = wave * BCH + c;
            gl2lds16(Bg + (size_t)(ch * 8) * ldb + k0, &Bs[ch * 512]);
        }
        __syncthreads();
#pragma unroll
        for (int h = 0; h < 2; h++) {
            bhalf8 af[MI], bf[NI];
#pragma unroll
            for (int mi = 0; mi < MI; mi++)
                af[mi] = *(bhalf8*)&As[(wr * WM + mi * 16 + l16) * 64 + h * 32 + quad * 8];
#pragma unroll
            for (int ni = 0; ni < NI; ni++)
                bf[ni] = *(bhalf8*)&Bs[(wc * WN + ni * 16 + l16) * 64 + h * 32 + quad * 8];
#pragma unroll
            for (int mi = 0; mi < MI; mi++)
#pragma unroll
                for (int ni = 0; ni < NI; ni++)
                    acc[mi][ni] = MFMA16(af[mi], bf[ni], acc[mi][ni]);
        }
    }

#pragma unroll
    for (int mi = 0; mi < MI; mi++)
#pragma unroll
        for (int ni = 0; ni < NI; ni++) {
            f32x4 a = acc[mi][ni];
            int gc = n0 + wc * WN + ni * 16 + l16;
            int gr0 = m0 + wr * WM + mi * 16 + quad * 4;
            float bsv = bias[gc];
            if (MODE == 0) {
                int mm = gc >> 9, cc = gc & 511;
                int hh = cc >> 6, e = cc & 63;
                int b = gr0 >> 11, s0 = gr0 & 2047;
                if (mm == 2) {
                    u64t pk = 0;
#pragma unroll
                    for (int r = 0; r < 4; r++) pk |= (u64t)f2b(a[r] + bsv) << (16 * r);
                    *(u64t*)&vtd[((size_t)(b * HH + hh) * HD + e) * SS + s0] = pk;
                } else if (mm == 0) {
#pragma unroll
                    for (int r = 0; r < 4; r++)
                        qd[((size_t)(b * HH + hh) * SS + s0 + r) * HD + e] = f2b((a[r] + bsv) * LOG2E);
                } else {
#pragma unroll
                    for (int r = 0; r < 4; r++)
                        kd[((size_t)(b * HH + hh) * SS + s0 + r) * HD + e] = f2b(a[r] + bsv);
                }
            } else if (MODE == 1) {
#pragma unroll
                for (int r = 0; r < 4; r++) {
                    size_t idx = (size_t)(gr0 + r) * N + gc;
                    outF[idx] = a[r] + bsv + resid[idx];
                }
            } else {
#pragma unroll
                for (int r = 0; r < 4; r++)
                    outB[(size_t)(gr0 + r) * N + gc] = f2b(fmaxf(a[r] + bsv, 0.0f));
            }
        }
}

// ---------------------------------------------------------------------------
// Flash attention v4 (round-7 proven): 512 threads = 8 waves in 2 kv-groups.
// q-tile 128 (32 q-rows/wave), kv-tile 128 split across groups (nt 0-3/4-7).
// K and V both staged coalesced into LDS. S^T trick, register prefetch,
// split-KV x2, no-max softmax (q pre-scaled by log2e). Group 1 merges into
// group 0 through dead Ks/Vs LDS at the epilogue. grid (16 bh, 16 qt, 2).
// ---------------------------------------------------------------------------
__global__ __launch_bounds__(512) void k_attention(const u16* __restrict__ q,
                                                   const u16* __restrict__ k,
                                                   const u16* __restrict__ vt,
                                                   float* __restrict__ Opart,
                                                   float* __restrict__ lsum) {
    __shared__ u16 sm[17920];                 // 35,840 B
    u16* Ks = sm;                             // 128*72 u16 = 18,432 B  [kv][hd]
    u16* Vs = sm + 9216;                      // 64*136 u16 = 17,408 B  [hd][kv]
    float* Ored = (float*)sm;                 // epilogue overlay: 8192 f32 (32 KB)
    float* Lred = (float*)sm + 8192;          // 128 f32

    int bh = blockIdx.x, qt = blockIdx.y, kspl = blockIdx.z;
    int t = threadIdx.x, wave = t >> 6, lane = t & 63, quad = lane >> 4, l16 = lane & 15;
    int g = wave >> 2, qw = wave & 3;         // kv-group, q-subtile
    const u16* qb = q  + (size_t)bh * SS * HD;
    const u16* kb = k  + (size_t)bh * SS * HD;
    const u16* vb = vt + (size_t)bh * HD * SS;

    // two q-chunks of 16 rows per wave (identical across groups)
    bhalf8 qfa0, qfa1, qfb0, qfb1;
    {
        int r0 = qt * 128 + qw * 32 + l16;
        qfa0 = *(const bhalf8*)(qb + (size_t)r0 * HD + quad * 8);
        qfa1 = *(const bhalf8*)(qb + (size_t)r0 * HD + 32 + quad * 8);
        qfb0 = *(const bhalf8*)(qb + (size_t)(r0 + 16) * HD + quad * 8);
        qfb1 = *(const bhalf8*)(qb + (size_t)(r0 + 16) * HD + 32 + quad * 8);
    }

    f32x4 oacc[2][4] = {};
    float rsa = 0.f, rsb = 0.f;

    // staging: 512 threads, 32B each for K and V
    int kr = t >> 2, kc = (t & 3) * 16;       // K: 128 rows x 64 cols
    int vr = t >> 3, vc = (t & 7) * 16;       // V: 64 rows x 128 cols
    const u16* kp = kb + ((size_t)kspl * 1024 + kr) * HD + kc;
    const u16* vp = vb + (size_t)vr * SS + kspl * 1024 + vc;
    u16* ksd = &Ks[kr * 72 + kc];
    u16* vsd = &Vs[vr * 136 + vc];

    bhalf8 kreg[2], vreg[2];
#pragma unroll
    for (int i = 0; i < 2; i++) {
        kreg[i] = *(const bhalf8*)(kp + i * 8);
        vreg[i] = *(const bhalf8*)(vp + i * 8);
    }

    for (int it = 0; it < 8; it++) {
        __syncthreads();
#pragma unroll
        for (int i = 0; i < 2; i++) {
            *(bhalf8*)(ksd + i * 8) = kreg[i];
            *(bhalf8*)(vsd + i * 8) = vreg[i];
        }
        __syncthreads();
        if (it < 7) {
            const u16* kn = kp + (size_t)(it + 1) * 128 * HD;
            const u16* vn = vp + (it + 1) * 128;
#pragma unroll
            for (int i = 0; i < 2; i++) {
                kreg[i] = *(const bhalf8*)(kn + i * 8);
                vreg[i] = *(const bhalf8*)(vn + i * 8);
            }
        }

#pragma unroll
        for (int nt2 = 0; nt2 < 4; nt2++) {
            int nt = g * 4 + nt2;
            bhalf8 kf0 = *(bhalf8*)&Ks[(nt * 16 + l16) * 72 + quad * 8];
            bhalf8 kf1 = *(bhalf8*)&Ks[(nt * 16 + l16) * 72 + 32 + quad * 8];
            // S^T = K·Q^T (C-layout: col=l16=q, row=quad*4+r=kv)
            f32x4 sa = {}, sb = {};
            sa = MFMA16(kf0, qfa0, sa);
            sa = MFMA16(kf1, qfa1, sa);
            sb = MFMA16(kf0, qfb0, sb);
            sb = MFMA16(kf1, qfb1, sb);
#if HAVE_K16
            union { bhalf4 v; u16 u[4]; } pa, pb;
#pragma unroll
            for (int r = 0; r < 4; r++) {
                float p0 = EXP2(sa[r]);
                float p1 = EXP2(sb[r]);
                rsa += p0; rsb += p1;
                pa.u[r] = f2b(p0); pb.u[r] = f2b(p1);
            }
#pragma unroll
            for (int et = 0; et < 4; et++) {
                bhalf4 vf = *(bhalf4*)&Vs[(et * 16 + l16) * 136 + nt * 16 + quad * 4];
                oacc[0][et] = MFMAK16(pa.v, vf, oacc[0][et]);
                oacc[1][et] = MFMAK16(pb.v, vf, oacc[1][et]);
            }
#else
            union { bhalf8 v; u16 u[8]; } pa, pb;
#pragma unroll
            for (int r = 0; r < 4; r++) {
                float p0 = EXP2(sa[r]);
                float p1 = EXP2(sb[r]);
                rsa += p0; rsb += p1;
                pa.u[r] = f2b(p0); pb.u[r] = f2b(p1);
            }
#pragma unroll
            for (int r = 4; r < 8; r++) { pa.u[r] = 0; pb.u[r] = 0; }
#pragma unroll
            for (int et = 0; et < 4; et++) {
                union { bhalf8 v; bhalf4 h[2]; } vf;
                vf.h[0] = *(bhalf4*)&Vs[(et * 16 + l16) * 136 + nt * 16 + quad * 4];
                vf.h[1] = (bhalf4){0, 0, 0, 0};
                oacc[0][et] = MFMA16(pa.v, vf.v, oacc[0][et]);
                oacc[1][et] = MFMA16(pb.v, vf.v, oacc[1][et]);
            }
#endif
        }
    }

    rsa += __shfl_xor(rsa, 16); rsa += __shfl_xor(rsa, 32);
    rsb += __shfl_xor(rsb, 16); rsb += __shfl_xor(rsb, 32);

    __syncthreads();   // Ks/Vs dead; overlay as Ored/Lred
    if (g == 1) {
#pragma unroll
        for (int qc = 0; qc < 2; qc++)
#pragma unroll
            for (int et = 0; et < 4; et++)
#pragma unroll
                for (int r = 0; r < 4; r++)
                    Ored[(qw * 32 + qc * 16 + quad * 4 + r) * 64 + et * 16 + l16] = oacc[qc][et][r];
        if (quad == 0) {
            Lred[qw * 32 + l16]      = rsa;
            Lred[qw * 32 + 16 + l16] = rsb;
        }
    }
    __syncthreads();
    if (g == 0) {
#pragma unroll
        for (int qc = 0; qc < 2; qc++) {
            int sbase = qt * 128 + qw * 32 + qc * 16;
            float* Ob = Opart + ((size_t)(kspl * 16 + bh) * SS + sbase) * HD;
#pragma unroll
            for (int et = 0; et < 4; et++)
#pragma unroll
                for (int r = 0; r < 4; r++) {
                    float v = oacc[qc][et][r]
                            + Ored[(qw * 32 + qc * 16 + quad * 4 + r) * 64 + et * 16 + l16];
                    Ob[(quad * 4 + r) * HD + et * 16 + l16] = v;
                }
            if (quad == 0)
                lsum[(size_t)(kspl * 16 + bh) * SS + sbase + l16] =
                    (qc == 0 ? rsa : rsb) + Lred[qw * 32 + qc * 16 + l16];
        }
    }
}

// combine: oc[b,s,h*64+e] = (O0+O1)/(l0+l1), bf16
__global__ __launch_bounds__(256) void k_combine(const float* __restrict__ Opart,
                                                 const float* __restrict__ lsum,
                                                 u16* __restrict__ oc) {
    int tid = blockIdx.x * 256 + threadIdx.x;
    int c4 = tid & 15, s = (tid >> 4) & 2047, bh = tid >> 15;
    size_t i0 = ((size_t)bh * SS + s) * HD + c4 * 4;
    float4 p0 = *(const float4*)(Opart + i0);
    float4 p1 = *(const float4*)(Opart + (size_t)16 * SS * HD + i0);
    float l = lsum[(size_t)bh * SS + s] + lsum[(size_t)16 * SS + (size_t)bh * SS + s];
    float inv = 1.0f / l;
    u64t pk = 0;
    pk |= (u64t)f2b((p0.x + p1.x) * inv);
    pk |= (u64t)f2b((p0.y + p1.y) * inv) << 16;
    pk |= (u64t)f2b((p0.z + p1.z) * inv) << 32;
    pk |= (u64t)f2b((p0.w + p1.w) * inv) << 48;
    int b = bh >> 3, h = bh & 7;
    *(u64t*)&oc[((size_t)b * SS + s) * DD + h * HD + c4 * 4] = pk;
}

// ---------------------------------------------------------------------------
extern "C" void kernel_launch(void* const* d_in, const int* in_sizes, int n_in,
                              void* d_out, int out_size, void* d_ws, size_t ws_size,
                              hipStream_t stream) {
    const float* x   = (const float*)d_in[0];
    const float* Wq  = (const float*)d_in[1];
    const float* bq  = (const float*)d_in[2];
    const float* Wk  = (const float*)d_in[3];
    const float* bk  = (const float*)d_in[4];
    const float* Wv  = (const float*)d_in[5];
    const float* bv  = (const float*)d_in[6];
    const float* Wp  = (const float*)d_in[7];
    const float* bp  = (const float*)d_in[8];
    const float* W1  = (const float*)d_in[9];
    const float* b1  = (const float*)d_in[10];
    const float* W2  = (const float*)d_in[11];
    const float* b2  = (const float*)d_in[12];
    const float* g1  = (const float*)d_in[13];
    const float* be1 = (const float*)d_in[14];
    const float* g2  = (const float*)d_in[15];
    const float* be2 = (const float*)d_in[16];

    char* ws = (char*)d_ws;
    u16*   WqkvT   = (u16*)(ws + 0);                    // 1,572,864
    u16*   WpT     = (u16*)(ws + 1572864);              //   524,288
    u16*   W1T     = (u16*)(ws + 2097152);              // 2,097,152
    u16*   W2T     = (u16*)(ws + 4194304);              // 2,097,152
    float* biasqkv = (float*)(ws + 6291456);            // 6,144
    u16*   xn      = (u16*)(ws + 6297600);              // 4,194,304 (reused: lsum)
    u16*   qB      = (u16*)(ws + 10491904);             // 4,194,304
    u16*   kB      = (u16*)(ws + 14686208);             // 4,194,304
    u16*   vTb     = (u16*)(ws + 18880512);             // 4,194,304  [bh,hd,S]
    u16*   oc      = (u16*)(ws + 23074816);             // 4,194,304
    float* x1      = (float*)(ws + 27269120);           // 8,388,608
    u16*   xn2     = (u16*)(ws + 35657728);             // 4,194,304
    u16*   hbuf    = (u16*)(ws + 39852032);             // 16,777,216 (Opart before MLP1)
    float* Opart   = (float*)hbuf;
    float* lsum    = (float*)xn;

    // prep (weights + bias concat) fused with LN1
    k_prep<<<4102, 256, 0, stream>>>(Wq, Wk, Wv, Wp, W1, W2, bq, bk, bv,
                                     WqkvT, WpT, W1T, W2T, biasqkv,
                                     x, g1, be1, xn);
    // QKV: 128x128 BK=64 m97-style, 32 MFMA/step, grid 384
    k_gemm<128, 128, 2, 2, 4, 4, 0><<<dim3(12, 32), 256, 0, stream>>>(
        xn, WqkvT, biasqkv, 512, 512, 512, 1536, nullptr, nullptr, nullptr, qB, kB, vTb);
    // attention: 8-wave v4, K+V LDS-staged, split-KV x2, grid 512
    k_attention<<<dim3(16, 16, 2), 512, 0, stream>>>(qB, kB, vTb, Opart, lsum);
    k_combine<<<2048, 256, 0, stream>>>(Opart, lsum, oc);
    // proj + residual: 64x64 BK=64, grid 512
    k_gemm<64, 64, 2, 2, 2, 2, 1><<<dim3(8, 64), 256, 0, stream>>>(
        oc, WpT, bp, 512, 512, 512, 512, x, x1, nullptr, nullptr, nullptr, nullptr);
    k_layernorm<<<NT / 4, 256, 0, stream>>>(x1, g2, be2, xn2);
    // MLP1: 128x128 BK=64, grid 512
    k_gemm<128, 128, 2, 2, 4, 4, 2><<<dim3(16, 32), 256, 0, stream>>>(
        xn2, W1T, b1, 512, 512, 512, 2048, nullptr, nullptr, hbuf, nullptr, nullptr, nullptr);
    // MLP2 + residual: 64x64 BK=64, K=2048, grid 512
    k_gemm<64, 64, 2, 2, 2, 2, 1><<<dim3(8, 64), 256, 0, stream>>>(
        hbuf, W2T, b2, 2048, 2048, 2048, 512, x1, (float*)d_out, nullptr, nullptr, nullptr, nullptr);
}